// Round 1
// baseline (153.231 us; speedup 1.0000x reference)
//
#include <hip/hip_runtime.h>

// Cascaded biquad IIR (DF2T), parallelized via linear state-space chunking:
//   phase 1: per-chunk final state from zero init (v_i)
//   phase 2: per-batch affine scan s_{i+1} = A^L s_i + v_i  (A^L built on device)
//   phase 3: per-chunk replay from exact initial state, write outputs

namespace {
constexpr int NS     = 4;            // biquad sections
constexpr int BATCH  = 512;
constexpr int TLEN   = 32768;
constexpr int P      = 128;          // chunks per batch
constexpr int L      = TLEN / P;     // 256 steps per chunk
constexpr int LOG2L  = 8;
static_assert((1 << LOG2L) == L, "L must be a power of two");
constexpr int NSTATE = 2 * NS;       // 8
}

__device__ __forceinline__ void load_coefs(const float* __restrict__ bc,
                                           const float* __restrict__ ac,
                                           float b0[NS], float b1[NS], float b2[NS],
                                           float a1[NS], float a2[NS]) {
#pragma unroll
  for (int k = 0; k < NS; ++k) {
    b0[k] = bc[3 * k];
    b1[k] = bc[3 * k + 1];
    b2[k] = bc[3 * k + 2];
    a1[k] = ac[2 * k];
    a2[k] = ac[2 * k + 1];
  }
}

// One time-step through the 4-section cascade. Matches reference:
//   y   = b0*u + s1
//   s1' = b1*u - a1*y + s2
//   s2' = b2*u - a2*y
__device__ __forceinline__ float step_cascade(float sig,
                                              const float b0[NS], const float b1[NS],
                                              const float b2[NS], const float a1[NS],
                                              const float a2[NS],
                                              float s1[NS], float s2[NS]) {
#pragma unroll
  for (int k = 0; k < NS; ++k) {
    float y = fmaf(b0[k], sig, s1[k]);
    s1[k]   = fmaf(-a1[k], y, fmaf(b1[k], sig, s2[k]));
    s2[k]   = fmaf(-a2[k], y, b2[k] * sig);
    sig = y;
  }
  return sig;
}

// ---------------------------------------------------------------------------
// Kernel 0: build M = A^L (8x8) on device. One block of 64 threads.
// State ordering: j = 2k -> s1[k], j = 2k+1 -> s2[k].
__global__ void k_build_M(const float* __restrict__ bc, const float* __restrict__ ac,
                          float* __restrict__ Mout) {
  __shared__ float Mm[NSTATE][NSTATE];
  const int tid = threadIdx.x;  // 64 threads
  float b0[NS], b1[NS], b2[NS], a1[NS], a2[NS];
  load_coefs(bc, ac, b0, b1, b2, a1, a2);

  if (tid < NSTATE) {
    // Column tid of A: one step with state = e_tid, input u = 0.
    float s1[NS] = {0.f, 0.f, 0.f, 0.f};
    float s2[NS] = {0.f, 0.f, 0.f, 0.f};
    if (tid & 1) s2[tid >> 1] = 1.0f; else s1[tid >> 1] = 1.0f;
    (void)step_cascade(0.0f, b0, b1, b2, a1, a2, s1, s2);
#pragma unroll
    for (int k = 0; k < NS; ++k) {
      Mm[2 * k][tid]     = s1[k];
      Mm[2 * k + 1][tid] = s2[k];
    }
  }
  __syncthreads();

  const int r = tid >> 3, c = tid & 7;  // 64 threads = one matrix element each
  for (int it = 0; it < LOG2L; ++it) {
    float acc = 0.0f;
#pragma unroll
    for (int k = 0; k < NSTATE; ++k) acc = fmaf(Mm[r][k], Mm[k][c], acc);
    __syncthreads();
    Mm[r][c] = acc;
    __syncthreads();
  }
  Mout[tid] = Mm[r][c];
}

// ---------------------------------------------------------------------------
// Phase 1: each thread (batch bi, chunk ci) runs its chunk from ZERO state,
// writes only the final 8-float state v to vbuf[tid*8].
__global__ __launch_bounds__(256) void k_chunk_state(const float* __restrict__ x,
                                                     const float* __restrict__ bc,
                                                     const float* __restrict__ ac,
                                                     float* __restrict__ vbuf) {
  const int tid = blockIdx.x * blockDim.x + threadIdx.x;  // BATCH * P threads
  const int bi  = tid / P;
  const int ci  = tid % P;
  float b0[NS], b1[NS], b2[NS], a1[NS], a2[NS];
  load_coefs(bc, ac, b0, b1, b2, a1, a2);

  const float* __restrict__ xp = x + (size_t)bi * TLEN + (size_t)ci * L;
  float s1[NS] = {0.f, 0.f, 0.f, 0.f};
  float s2[NS] = {0.f, 0.f, 0.f, 0.f};

  for (int t = 0; t < L; t += 4) {
    const float4 xv = *reinterpret_cast<const float4*>(xp + t);
    const float xs[4] = {xv.x, xv.y, xv.z, xv.w};
#pragma unroll
    for (int j = 0; j < 4; ++j)
      (void)step_cascade(xs[j], b0, b1, b2, a1, a2, s1, s2);
  }

  float* __restrict__ vp = vbuf + (size_t)tid * NSTATE;
  *reinterpret_cast<float4*>(vp)     = make_float4(s1[0], s2[0], s1[1], s2[1]);
  *reinterpret_cast<float4*>(vp + 4) = make_float4(s1[2], s2[2], s1[3], s2[3]);
}

// ---------------------------------------------------------------------------
// Phase 2: per-batch sequential affine scan over P chunks:
//   s_init(0) = 0;  s_init(i+1) = M * s_init(i) + v_i
// Overwrites vbuf slot i with s_init(i) (read v_i first; same thread, no race).
__global__ __launch_bounds__(256) void k_scan(const float* __restrict__ Mmat,
                                              float* __restrict__ vbuf) {
  __shared__ float Mm[NSTATE * NSTATE];
  if (threadIdx.x < NSTATE * NSTATE) Mm[threadIdx.x] = Mmat[threadIdx.x];
  __syncthreads();

  const int bi = blockIdx.x * blockDim.x + threadIdx.x;
  if (bi >= BATCH) return;

  float M[NSTATE][NSTATE];
#pragma unroll
  for (int r = 0; r < NSTATE; ++r)
#pragma unroll
    for (int c = 0; c < NSTATE; ++c) M[r][c] = Mm[r * NSTATE + c];

  float s[NSTATE] = {0.f, 0.f, 0.f, 0.f, 0.f, 0.f, 0.f, 0.f};
  float* __restrict__ vp = vbuf + (size_t)bi * P * NSTATE;

  for (int i = 0; i < P; ++i) {
    const float4 va = *reinterpret_cast<const float4*>(vp + i * NSTATE);
    const float4 vb = *reinterpret_cast<const float4*>(vp + i * NSTATE + 4);
    const float v[NSTATE] = {va.x, va.y, va.z, va.w, vb.x, vb.y, vb.z, vb.w};

    float sn[NSTATE];
#pragma unroll
    for (int r = 0; r < NSTATE; ++r) {
      float acc = v[r];
#pragma unroll
      for (int k = 0; k < NSTATE; ++k) acc = fmaf(M[r][k], s[k], acc);
      sn[r] = acc;
    }

    // store s_init for chunk i (state BEFORE chunk i)
    *reinterpret_cast<float4*>(vp + i * NSTATE)     = make_float4(s[0], s[1], s[2], s[3]);
    *reinterpret_cast<float4*>(vp + i * NSTATE + 4) = make_float4(s[4], s[5], s[6], s[7]);
#pragma unroll
    for (int r = 0; r < NSTATE; ++r) s[r] = sn[r];
  }
}

// ---------------------------------------------------------------------------
// Phase 3: replay each chunk from its exact initial state, write outputs.
__global__ __launch_bounds__(256) void k_chunk_out(const float* __restrict__ x,
                                                   const float* __restrict__ bc,
                                                   const float* __restrict__ ac,
                                                   const float* __restrict__ sbuf,
                                                   float* __restrict__ out) {
  const int tid = blockIdx.x * blockDim.x + threadIdx.x;
  const int bi  = tid / P;
  const int ci  = tid % P;
  float b0[NS], b1[NS], b2[NS], a1[NS], a2[NS];
  load_coefs(bc, ac, b0, b1, b2, a1, a2);

  const float* __restrict__ sp = sbuf + (size_t)tid * NSTATE;
  const float4 sa = *reinterpret_cast<const float4*>(sp);
  const float4 sb = *reinterpret_cast<const float4*>(sp + 4);
  float s1[NS] = {sa.x, sa.z, sb.x, sb.z};
  float s2[NS] = {sa.y, sa.w, sb.y, sb.w};

  const float* __restrict__ xp = x + (size_t)bi * TLEN + (size_t)ci * L;
  float* __restrict__ op       = out + (size_t)bi * TLEN + (size_t)ci * L;

  for (int t = 0; t < L; t += 4) {
    const float4 xv = *reinterpret_cast<const float4*>(xp + t);
    const float xs[4] = {xv.x, xv.y, xv.z, xv.w};
    float ys[4];
#pragma unroll
    for (int j = 0; j < 4; ++j)
      ys[j] = step_cascade(xs[j], b0, b1, b2, a1, a2, s1, s2);
    *reinterpret_cast<float4*>(op + t) = make_float4(ys[0], ys[1], ys[2], ys[3]);
  }
}

// ---------------------------------------------------------------------------
// Fallback (ws too small): one thread per batch, fully sequential. Correct
// but slow (~200us); only used if ws_size < ~2.1 MB.
__global__ void k_naive(const float* __restrict__ x, const float* __restrict__ bc,
                        const float* __restrict__ ac, float* __restrict__ out) {
  const int bi = blockIdx.x * blockDim.x + threadIdx.x;
  if (bi >= BATCH) return;
  float b0[NS], b1[NS], b2[NS], a1[NS], a2[NS];
  load_coefs(bc, ac, b0, b1, b2, a1, a2);
  float s1[NS] = {0.f, 0.f, 0.f, 0.f};
  float s2[NS] = {0.f, 0.f, 0.f, 0.f};
  const float* __restrict__ xp = x + (size_t)bi * TLEN;
  float* __restrict__ op       = out + (size_t)bi * TLEN;
  for (int t = 0; t < TLEN; t += 4) {
    const float4 xv = *reinterpret_cast<const float4*>(xp + t);
    const float xs[4] = {xv.x, xv.y, xv.z, xv.w};
    float ys[4];
#pragma unroll
    for (int j = 0; j < 4; ++j)
      ys[j] = step_cascade(xs[j], b0, b1, b2, a1, a2, s1, s2);
    *reinterpret_cast<float4*>(op + t) = make_float4(ys[0], ys[1], ys[2], ys[3]);
  }
}

extern "C" void kernel_launch(void* const* d_in, const int* in_sizes, int n_in,
                              void* d_out, int out_size, void* d_ws, size_t ws_size,
                              hipStream_t stream) {
  const float* x  = (const float*)d_in[0];  // (B, T, 1)
  const float* bc = (const float*)d_in[1];  // (NS, 3)
  const float* ac = (const float*)d_in[2];  // (NS, 2)
  float* out = (float*)d_out;               // (B, T, 1)

  const size_t need =
      (size_t)(BATCH * P * NSTATE + NSTATE * NSTATE) * sizeof(float);
  if (ws_size < need) {
    k_naive<<<(BATCH + 255) / 256, 256, 0, stream>>>(x, bc, ac, out);
    return;
  }

  float* vbuf = (float*)d_ws;                         // BATCH*P*8 floats
  float* Mmat = vbuf + (size_t)BATCH * P * NSTATE;    // 64 floats

  k_build_M<<<1, 64, 0, stream>>>(bc, ac, Mmat);
  k_chunk_state<<<(BATCH * P) / 256, 256, 0, stream>>>(x, bc, ac, vbuf);
  k_scan<<<(BATCH + 255) / 256, 256, 0, stream>>>(Mmat, vbuf);
  k_chunk_out<<<(BATCH * P) / 256, 256, 0, stream>>>(x, bc, ac, vbuf, out);
}

// Round 2
// 74.388 us; speedup vs baseline: 2.0599x; 2.0599x over previous
//
#include <hip/hip_runtime.h>

// Cascaded biquad IIR (DF2T), parallelized via linear state-space chunking:
//   phase 0: build M_d = (A^L)^(2^d), d = 0..log2(P)-1  (on device, 1 block)
//   phase 1: per-chunk final state from zero init (v_i)
//   phase 2: Kogge-Stone parallel affine scan across chunks (per batch)
//   phase 3: per-chunk replay from exact initial state, write outputs

namespace {
constexpr int NS     = 4;            // biquad sections
constexpr int BATCH  = 512;
constexpr int TLEN   = 32768;        // 2^15
constexpr int LOG2T  = 15;
constexpr int NSTATE = 2 * NS;       // 8
}

__device__ __forceinline__ void load_coefs(const float* __restrict__ bc,
                                           const float* __restrict__ ac,
                                           float b0[NS], float b1[NS], float b2[NS],
                                           float a1[NS], float a2[NS]) {
#pragma unroll
  for (int k = 0; k < NS; ++k) {
    b0[k] = bc[3 * k];
    b1[k] = bc[3 * k + 1];
    b2[k] = bc[3 * k + 2];
    a1[k] = ac[2 * k];
    a2[k] = ac[2 * k + 1];
  }
}

// One time-step through the 4-section cascade (matches reference exactly).
__device__ __forceinline__ float step_cascade(float sig,
                                              const float b0[NS], const float b1[NS],
                                              const float b2[NS], const float a1[NS],
                                              const float a2[NS],
                                              float s1[NS], float s2[NS]) {
#pragma unroll
  for (int k = 0; k < NS; ++k) {
    float y = fmaf(b0[k], sig, s1[k]);
    s1[k]   = fmaf(-a1[k], y, fmaf(b1[k], sig, s2[k]));
    s2[k]   = fmaf(-a2[k], y, b2[k] * sig);
    sig = y;
  }
  return sig;
}

// ---------------------------------------------------------------------------
// Phase 0: build M_d = (A^L)^(2^d) for d = 0..NPOW-1.  One block, 64 threads.
// State ordering: j = 2k -> s1[k], j = 2k+1 -> s2[k].  Mout: [NPOW][64].
template <int LOG2L, int NPOW>
__global__ void k_build_M(const float* __restrict__ bc, const float* __restrict__ ac,
                          float* __restrict__ Mout) {
  __shared__ float Mm[NSTATE][NSTATE];
  const int tid = threadIdx.x;  // 64 threads
  float b0[NS], b1[NS], b2[NS], a1[NS], a2[NS];
  load_coefs(bc, ac, b0, b1, b2, a1, a2);

  if (tid < NSTATE) {
    // Column tid of A: one step with state = e_tid, input u = 0.
    float s1[NS] = {0.f, 0.f, 0.f, 0.f};
    float s2[NS] = {0.f, 0.f, 0.f, 0.f};
    if (tid & 1) s2[tid >> 1] = 1.0f; else s1[tid >> 1] = 1.0f;
    (void)step_cascade(0.0f, b0, b1, b2, a1, a2, s1, s2);
#pragma unroll
    for (int k = 0; k < NS; ++k) {
      Mm[2 * k][tid]     = s1[k];
      Mm[2 * k + 1][tid] = s2[k];
    }
  }
  __syncthreads();

  const int r = tid >> 3, c = tid & 7;  // one matrix element per thread
  // LOG2L squarings produce A^L (store as d=0), each further squaring = next d.
  for (int it = 0; it < LOG2L + NPOW - 1; ++it) {
    float acc = 0.0f;
#pragma unroll
    for (int k = 0; k < NSTATE; ++k) acc = fmaf(Mm[r][k], Mm[k][c], acc);
    __syncthreads();
    Mm[r][c] = acc;
    __syncthreads();
    if (it >= LOG2L - 1) Mout[(it - (LOG2L - 1)) * 64 + tid] = acc;
  }
}

// ---------------------------------------------------------------------------
// Phase 1: thread (bi, ci) runs its chunk from ZERO state, writes final state.
template <int P>
__global__ __launch_bounds__(256) void k_chunk_state(const float* __restrict__ x,
                                                     const float* __restrict__ bc,
                                                     const float* __restrict__ ac,
                                                     float* __restrict__ vbuf) {
  constexpr int L  = TLEN / P;
  constexpr int NV = L / 4;
  const int tid = blockIdx.x * blockDim.x + threadIdx.x;  // BATCH * P threads
  const int bi  = tid / P;
  const int ci  = tid % P;
  float b0[NS], b1[NS], b2[NS], a1[NS], a2[NS];
  load_coefs(bc, ac, b0, b1, b2, a1, a2);

  const float4* __restrict__ xp4 =
      reinterpret_cast<const float4*>(x + (size_t)bi * TLEN + (size_t)ci * L);
  float s1[NS] = {0.f, 0.f, 0.f, 0.f};
  float s2[NS] = {0.f, 0.f, 0.f, 0.f};

  float4 buf[4] = {xp4[0], xp4[1], xp4[2], xp4[3]};
  for (int t0 = 0; t0 < NV; t0 += 4) {
#pragma unroll
    for (int j = 0; j < 4; ++j) {
      const float4 cur = buf[j];
      if (t0 + 4 + j < NV) buf[j] = xp4[t0 + 4 + j];  // keep 4 loads in flight
      (void)step_cascade(cur.x, b0, b1, b2, a1, a2, s1, s2);
      (void)step_cascade(cur.y, b0, b1, b2, a1, a2, s1, s2);
      (void)step_cascade(cur.z, b0, b1, b2, a1, a2, s1, s2);
      (void)step_cascade(cur.w, b0, b1, b2, a1, a2, s1, s2);
    }
  }

  float* __restrict__ vp = vbuf + (size_t)tid * NSTATE;
  *reinterpret_cast<float4*>(vp)     = make_float4(s1[0], s2[0], s1[1], s2[1]);
  *reinterpret_cast<float4*>(vp + 4) = make_float4(s1[2], s2[2], s1[3], s2[3]);
}

// ---------------------------------------------------------------------------
// Phase 2: Kogge-Stone affine scan across the P chunks of each batch.
//   inclusive w_i = state after chunk i (from zero init at t=0)
//   update: w_i <- M_d * w_{i-2^d} + w_i
//   result written back: vbuf slot i <- s_init(i) = (i==0 ? 0 : w_{i-1})
template <int P, int LOG2P>
__global__ __launch_bounds__(256) void k_scan_par(const float* __restrict__ Mpows,
                                                  float* __restrict__ vbuf) {
  constexpr int BPB = 256 / P;  // batches per block
  __shared__ float Ms[LOG2P][64];
  __shared__ float W[256][NSTATE + 1];  // +1 pad: stride 9 -> 2-way bank alias (free)
  const int t = threadIdx.x;
  for (int i = t; i < LOG2P * 64; i += 256) Ms[i >> 6][i & 63] = Mpows[i];

  const int sub = t / P;
  const int ci  = t % P;
  const int bi  = blockIdx.x * BPB + sub;
  float* __restrict__ vp = vbuf + ((size_t)bi * P + ci) * NSTATE;

  float w[NSTATE];
  {
    const float4 va = *reinterpret_cast<const float4*>(vp);
    const float4 vb = *reinterpret_cast<const float4*>(vp + 4);
    w[0] = va.x; w[1] = va.y; w[2] = va.z; w[3] = va.w;
    w[4] = vb.x; w[5] = vb.y; w[6] = vb.z; w[7] = vb.w;
  }
  __syncthreads();  // Ms ready

  for (int d = 0; d < LOG2P; ++d) {
#pragma unroll
    for (int r = 0; r < NSTATE; ++r) W[t][r] = w[r];
    __syncthreads();
    if (ci >= (1 << d)) {
      const int src = t - (1 << d);
      float prev[NSTATE];
#pragma unroll
      for (int r = 0; r < NSTATE; ++r) prev[r] = W[src][r];
#pragma unroll
      for (int r = 0; r < NSTATE; ++r) {
        float acc = w[r];
#pragma unroll
        for (int k = 0; k < NSTATE; ++k)
          acc = fmaf(Ms[d][r * NSTATE + k], prev[k], acc);  // broadcast read: free
        w[r] = acc;
      }
    }
    __syncthreads();
  }

  // exclusive shift
#pragma unroll
  for (int r = 0; r < NSTATE; ++r) W[t][r] = w[r];
  __syncthreads();
  float s[NSTATE];
  if (ci == 0) {
#pragma unroll
    for (int r = 0; r < NSTATE; ++r) s[r] = 0.0f;
  } else {
#pragma unroll
    for (int r = 0; r < NSTATE; ++r) s[r] = W[t - 1][r];
  }
  *reinterpret_cast<float4*>(vp)     = make_float4(s[0], s[1], s[2], s[3]);
  *reinterpret_cast<float4*>(vp + 4) = make_float4(s[4], s[5], s[6], s[7]);
}

// ---------------------------------------------------------------------------
// Phase 3: replay each chunk from its exact initial state, write outputs.
template <int P>
__global__ __launch_bounds__(256) void k_chunk_out(const float* __restrict__ x,
                                                   const float* __restrict__ bc,
                                                   const float* __restrict__ ac,
                                                   const float* __restrict__ sbuf,
                                                   float* __restrict__ out) {
  constexpr int L  = TLEN / P;
  constexpr int NV = L / 4;
  const int tid = blockIdx.x * blockDim.x + threadIdx.x;
  const int bi  = tid / P;
  const int ci  = tid % P;
  float b0[NS], b1[NS], b2[NS], a1[NS], a2[NS];
  load_coefs(bc, ac, b0, b1, b2, a1, a2);

  const float* __restrict__ sp = sbuf + (size_t)tid * NSTATE;
  const float4 sa = *reinterpret_cast<const float4*>(sp);
  const float4 sb = *reinterpret_cast<const float4*>(sp + 4);
  float s1[NS] = {sa.x, sa.z, sb.x, sb.z};
  float s2[NS] = {sa.y, sa.w, sb.y, sb.w};

  const float4* __restrict__ xp4 =
      reinterpret_cast<const float4*>(x + (size_t)bi * TLEN + (size_t)ci * L);
  float4* __restrict__ op4 =
      reinterpret_cast<float4*>(out + (size_t)bi * TLEN + (size_t)ci * L);

  float4 buf[4] = {xp4[0], xp4[1], xp4[2], xp4[3]};
  for (int t0 = 0; t0 < NV; t0 += 4) {
#pragma unroll
    for (int j = 0; j < 4; ++j) {
      const float4 cur = buf[j];
      if (t0 + 4 + j < NV) buf[j] = xp4[t0 + 4 + j];
      float4 yv;
      yv.x = step_cascade(cur.x, b0, b1, b2, a1, a2, s1, s2);
      yv.y = step_cascade(cur.y, b0, b1, b2, a1, a2, s1, s2);
      yv.z = step_cascade(cur.z, b0, b1, b2, a1, a2, s1, s2);
      yv.w = step_cascade(cur.w, b0, b1, b2, a1, a2, s1, s2);
      op4[t0 + j] = yv;
    }
  }
}

// ---------------------------------------------------------------------------
// Fallback (ws too small): one thread per batch, fully sequential but correct.
__global__ void k_naive(const float* __restrict__ x, const float* __restrict__ bc,
                        const float* __restrict__ ac, float* __restrict__ out) {
  const int bi = blockIdx.x * blockDim.x + threadIdx.x;
  if (bi >= BATCH) return;
  float b0[NS], b1[NS], b2[NS], a1[NS], a2[NS];
  load_coefs(bc, ac, b0, b1, b2, a1, a2);
  float s1[NS] = {0.f, 0.f, 0.f, 0.f};
  float s2[NS] = {0.f, 0.f, 0.f, 0.f};
  const float* __restrict__ xp = x + (size_t)bi * TLEN;
  float* __restrict__ op       = out + (size_t)bi * TLEN;
  for (int t = 0; t < TLEN; t += 4) {
    const float4 xv = *reinterpret_cast<const float4*>(xp + t);
    float ys[4];
    ys[0] = step_cascade(xv.x, b0, b1, b2, a1, a2, s1, s2);
    ys[1] = step_cascade(xv.y, b0, b1, b2, a1, a2, s1, s2);
    ys[2] = step_cascade(xv.z, b0, b1, b2, a1, a2, s1, s2);
    ys[3] = step_cascade(xv.w, b0, b1, b2, a1, a2, s1, s2);
    *reinterpret_cast<float4*>(op + t) = make_float4(ys[0], ys[1], ys[2], ys[3]);
  }
}

// ---------------------------------------------------------------------------
template <int P, int LOG2P>
static void run_pipeline(const float* x, const float* bc, const float* ac,
                         float* out, void* d_ws, hipStream_t stream) {
  constexpr int LOG2L = LOG2T - LOG2P;
  float* vbuf = (float*)d_ws;                          // BATCH*P*8 floats
  float* Mmat = vbuf + (size_t)BATCH * P * NSTATE;     // LOG2P*64 floats

  k_build_M<LOG2L, LOG2P><<<1, 64, 0, stream>>>(bc, ac, Mmat);
  k_chunk_state<P><<<(BATCH * P) / 256, 256, 0, stream>>>(x, bc, ac, vbuf);
  k_scan_par<P, LOG2P><<<(BATCH * P) / 256, 256, 0, stream>>>(Mmat, vbuf);
  k_chunk_out<P><<<(BATCH * P) / 256, 256, 0, stream>>>(x, bc, ac, vbuf, out);
}

extern "C" void kernel_launch(void* const* d_in, const int* in_sizes, int n_in,
                              void* d_out, int out_size, void* d_ws, size_t ws_size,
                              hipStream_t stream) {
  const float* x  = (const float*)d_in[0];  // (B, T, 1)
  const float* bc = (const float*)d_in[1];  // (NS, 3)
  const float* ac = (const float*)d_in[2];  // (NS, 2)
  float* out = (float*)d_out;               // (B, T, 1)

  const size_t need256 = ((size_t)BATCH * 256 * NSTATE + 8 * 64) * sizeof(float);
  const size_t need128 = ((size_t)BATCH * 128 * NSTATE + 7 * 64) * sizeof(float);

  if (ws_size >= need256) {
    run_pipeline<256, 8>(x, bc, ac, out, d_ws, stream);
  } else if (ws_size >= need128) {
    run_pipeline<128, 7>(x, bc, ac, out, d_ws, stream);
  } else {
    k_naive<<<(BATCH + 255) / 256, 256, 0, stream>>>(x, bc, ac, out);
  }
}

// Round 3
// 71.412 us; speedup vs baseline: 2.1457x; 1.0417x over previous
//
#include <hip/hip_runtime.h>

// Cascaded biquad IIR (DF2T), parallelized via linear state-space chunking:
//   phase 0: build M_d = (A^L)^(2^d)  (on device, 1 block)
//   phase 1: per-chunk final state from zero init (LDS-staged coalesced reads)
//   phase 2: Kogge-Stone parallel affine scan across chunks (per batch)
//   phase 3: per-chunk replay from exact initial state (LDS-staged both ways)

namespace {
constexpr int NS     = 4;            // biquad sections
constexpr int BATCH  = 512;
constexpr int TLEN   = 32768;        // 2^15
constexpr int LOG2T  = 15;
constexpr int NSTATE = 2 * NS;       // 8
constexpr int TT     = 16;           // time-steps per LDS tile
constexpr int TQ     = TT / 4;       // float4s per chunk per tile (4)
constexpr int RS     = TQ + 1;       // LDS row stride in float4 (pad -> stride-1-like banks)
}

__device__ __forceinline__ void load_coefs(const float* __restrict__ bc,
                                           const float* __restrict__ ac,
                                           float b0[NS], float b1[NS], float b2[NS],
                                           float a1[NS], float a2[NS]) {
#pragma unroll
  for (int k = 0; k < NS; ++k) {
    b0[k] = bc[3 * k];
    b1[k] = bc[3 * k + 1];
    b2[k] = bc[3 * k + 2];
    a1[k] = ac[2 * k];
    a2[k] = ac[2 * k + 1];
  }
}

// One time-step through the 4-section cascade (matches reference exactly).
__device__ __forceinline__ float step_cascade(float sig,
                                              const float b0[NS], const float b1[NS],
                                              const float b2[NS], const float a1[NS],
                                              const float a2[NS],
                                              float s1[NS], float s2[NS]) {
#pragma unroll
  for (int k = 0; k < NS; ++k) {
    float y = fmaf(b0[k], sig, s1[k]);
    s1[k]   = fmaf(-a1[k], y, fmaf(b1[k], sig, s2[k]));
    s2[k]   = fmaf(-a2[k], y, b2[k] * sig);
    sig = y;
  }
  return sig;
}

// ---------------------------------------------------------------------------
// Phase 0: build M_d = (A^L)^(2^d) for d = 0..NPOW-1.  One block, 64 threads.
// State ordering: j = 2k -> s1[k], j = 2k+1 -> s2[k].  Mout: [NPOW][64].
template <int LOG2L, int NPOW>
__global__ void k_build_M(const float* __restrict__ bc, const float* __restrict__ ac,
                          float* __restrict__ Mout) {
  __shared__ float Mm[NSTATE][NSTATE];
  const int tid = threadIdx.x;  // 64 threads
  float b0[NS], b1[NS], b2[NS], a1[NS], a2[NS];
  load_coefs(bc, ac, b0, b1, b2, a1, a2);

  if (tid < NSTATE) {
    float s1[NS] = {0.f, 0.f, 0.f, 0.f};
    float s2[NS] = {0.f, 0.f, 0.f, 0.f};
    if (tid & 1) s2[tid >> 1] = 1.0f; else s1[tid >> 1] = 1.0f;
    (void)step_cascade(0.0f, b0, b1, b2, a1, a2, s1, s2);
#pragma unroll
    for (int k = 0; k < NS; ++k) {
      Mm[2 * k][tid]     = s1[k];
      Mm[2 * k + 1][tid] = s2[k];
    }
  }
  __syncthreads();

  const int r = tid >> 3, c = tid & 7;
  for (int it = 0; it < LOG2L + NPOW - 1; ++it) {
    float acc = 0.0f;
#pragma unroll
    for (int k = 0; k < NSTATE; ++k) acc = fmaf(Mm[r][k], Mm[k][c], acc);
    __syncthreads();
    Mm[r][c] = acc;
    __syncthreads();
    if (it >= LOG2L - 1) Mout[(it - (LOG2L - 1)) * 64 + tid] = acc;
  }
}

// ---------------------------------------------------------------------------
// Phase 1: 256 threads/block = 256 consecutive chunks. LDS-staged coalesced
// reads; each thread runs its chunk from ZERO state; writes final state v.
template <int P>
__global__ __launch_bounds__(256, 4) void k_chunk_state(const float* __restrict__ x,
                                                        const float* __restrict__ bc,
                                                        const float* __restrict__ ac,
                                                        float* __restrict__ vbuf) {
  constexpr int L   = TLEN / P;
  constexpr int LQ  = L / 4;       // float4s per chunk
  constexpr int NTL = L / TT;      // tiles
  __shared__ float4 lin[256 * RS];

  const int t   = threadIdx.x;
  const int gtid = blockIdx.x * 256 + t;
  float b0[NS], b1[NS], b2[NS], a1[NS], a2[NS];
  load_coefs(bc, ac, b0, b1, b2, a1, a2);

  // flat x index of chunk gtid starts at gtid*L (since TLEN = P*L).
  const float4* __restrict__ gsrc =
      reinterpret_cast<const float4*>(x) + (size_t)blockIdx.x * 256 * LQ;

  float s1[NS] = {0.f, 0.f, 0.f, 0.f};
  float s2[NS] = {0.f, 0.f, 0.f, 0.f};

  for (int tile = 0; tile < NTL; ++tile) {
    const int t0q = tile * TQ;
    // stage-in: 64B-coalesced (4 consecutive lanes cover one chunk's 64B)
#pragma unroll
    for (int q = 0; q < TQ; ++q) {
      const int m  = t + 256 * q;
      const int c  = m >> 2;
      const int tq = m & 3;
      lin[c * RS + tq] = gsrc[(size_t)c * LQ + t0q + tq];
    }
    __syncthreads();
    // compute TT steps out of LDS
#pragma unroll
    for (int tq = 0; tq < TQ; ++tq) {
      const float4 u = lin[t * RS + tq];
      (void)step_cascade(u.x, b0, b1, b2, a1, a2, s1, s2);
      (void)step_cascade(u.y, b0, b1, b2, a1, a2, s1, s2);
      (void)step_cascade(u.z, b0, b1, b2, a1, a2, s1, s2);
      (void)step_cascade(u.w, b0, b1, b2, a1, a2, s1, s2);
    }
    __syncthreads();
  }

  float* __restrict__ vp = vbuf + (size_t)gtid * NSTATE;
  *reinterpret_cast<float4*>(vp)     = make_float4(s1[0], s2[0], s1[1], s2[1]);
  *reinterpret_cast<float4*>(vp + 4) = make_float4(s1[2], s2[2], s1[3], s2[3]);
}

// ---------------------------------------------------------------------------
// Phase 2: Kogge-Stone affine scan across the P chunks of each batch.
//   w_i <- M_d * w_{i-2^d} + w_i ; writeback slot i <- s_init(i)
template <int P, int LOG2P>
__global__ void k_scan_par(const float* __restrict__ Mpows,
                           float* __restrict__ vbuf) {
  constexpr int THREADS = (P > 256) ? P : 256;
  constexpr int BPB     = THREADS / P;  // batches per block
  __shared__ float Ms[LOG2P][64];
  __shared__ float W[THREADS][NSTATE + 1];  // stride 9 -> 2-way alias (free)
  const int t = threadIdx.x;
  for (int i = t; i < LOG2P * 64; i += THREADS) Ms[i >> 6][i & 63] = Mpows[i];

  const int sub = t / P;
  const int ci  = t % P;
  const int bi  = blockIdx.x * BPB + sub;
  float* __restrict__ vp = vbuf + ((size_t)bi * P + ci) * NSTATE;

  float w[NSTATE];
  {
    const float4 va = *reinterpret_cast<const float4*>(vp);
    const float4 vb = *reinterpret_cast<const float4*>(vp + 4);
    w[0] = va.x; w[1] = va.y; w[2] = va.z; w[3] = va.w;
    w[4] = vb.x; w[5] = vb.y; w[6] = vb.z; w[7] = vb.w;
  }
  __syncthreads();  // Ms ready

  for (int d = 0; d < LOG2P; ++d) {
#pragma unroll
    for (int r = 0; r < NSTATE; ++r) W[t][r] = w[r];
    __syncthreads();
    if (ci >= (1 << d)) {
      const int src = t - (1 << d);
      float prev[NSTATE];
#pragma unroll
      for (int r = 0; r < NSTATE; ++r) prev[r] = W[src][r];
#pragma unroll
      for (int r = 0; r < NSTATE; ++r) {
        float acc = w[r];
#pragma unroll
        for (int k = 0; k < NSTATE; ++k)
          acc = fmaf(Ms[d][r * NSTATE + k], prev[k], acc);  // broadcast: free
        w[r] = acc;
      }
    }
    __syncthreads();
  }

  // exclusive shift
#pragma unroll
  for (int r = 0; r < NSTATE; ++r) W[t][r] = w[r];
  __syncthreads();
  float s[NSTATE];
  if (ci == 0) {
#pragma unroll
    for (int r = 0; r < NSTATE; ++r) s[r] = 0.0f;
  } else {
#pragma unroll
    for (int r = 0; r < NSTATE; ++r) s[r] = W[t - 1][r];
  }
  *reinterpret_cast<float4*>(vp)     = make_float4(s[0], s[1], s[2], s[3]);
  *reinterpret_cast<float4*>(vp + 4) = make_float4(s[4], s[5], s[6], s[7]);
}

// ---------------------------------------------------------------------------
// Phase 3: replay each chunk from its exact initial state; LDS-staged
// coalesced reads AND writes (fixes the 104MB write amplification).
template <int P>
__global__ __launch_bounds__(256, 4) void k_chunk_out(const float* __restrict__ x,
                                                      const float* __restrict__ bc,
                                                      const float* __restrict__ ac,
                                                      const float* __restrict__ sbuf,
                                                      float* __restrict__ out) {
  constexpr int L   = TLEN / P;
  constexpr int LQ  = L / 4;
  constexpr int NTL = L / TT;
  __shared__ float4 lin[256 * RS];
  __shared__ float4 lout[256 * RS];

  const int t    = threadIdx.x;
  const int gtid = blockIdx.x * 256 + t;
  float b0[NS], b1[NS], b2[NS], a1[NS], a2[NS];
  load_coefs(bc, ac, b0, b1, b2, a1, a2);

  const float* __restrict__ sp = sbuf + (size_t)gtid * NSTATE;
  const float4 sa = *reinterpret_cast<const float4*>(sp);
  const float4 sb = *reinterpret_cast<const float4*>(sp + 4);
  float s1[NS] = {sa.x, sa.z, sb.x, sb.z};
  float s2[NS] = {sa.y, sa.w, sb.y, sb.w};

  const float4* __restrict__ gsrc =
      reinterpret_cast<const float4*>(x) + (size_t)blockIdx.x * 256 * LQ;
  float4* __restrict__ gdst =
      reinterpret_cast<float4*>(out) + (size_t)blockIdx.x * 256 * LQ;

  for (int tile = 0; tile < NTL; ++tile) {
    const int t0q = tile * TQ;
#pragma unroll
    for (int q = 0; q < TQ; ++q) {
      const int m  = t + 256 * q;
      const int c  = m >> 2;
      const int tq = m & 3;
      lin[c * RS + tq] = gsrc[(size_t)c * LQ + t0q + tq];
    }
    __syncthreads();
#pragma unroll
    for (int tq = 0; tq < TQ; ++tq) {
      const float4 u = lin[t * RS + tq];
      float4 y;
      y.x = step_cascade(u.x, b0, b1, b2, a1, a2, s1, s2);
      y.y = step_cascade(u.y, b0, b1, b2, a1, a2, s1, s2);
      y.z = step_cascade(u.z, b0, b1, b2, a1, a2, s1, s2);
      y.w = step_cascade(u.w, b0, b1, b2, a1, a2, s1, s2);
      lout[t * RS + tq] = y;
    }
    __syncthreads();
#pragma unroll
    for (int q = 0; q < TQ; ++q) {
      const int m  = t + 256 * q;
      const int c  = m >> 2;
      const int tq = m & 3;
      gdst[(size_t)c * LQ + t0q + tq] = lout[c * RS + tq];
    }
    __syncthreads();
  }
}

// ---------------------------------------------------------------------------
// Fallback (ws too small): one thread per batch, fully sequential but correct.
__global__ void k_naive(const float* __restrict__ x, const float* __restrict__ bc,
                        const float* __restrict__ ac, float* __restrict__ out) {
  const int bi = blockIdx.x * blockDim.x + threadIdx.x;
  if (bi >= BATCH) return;
  float b0[NS], b1[NS], b2[NS], a1[NS], a2[NS];
  load_coefs(bc, ac, b0, b1, b2, a1, a2);
  float s1[NS] = {0.f, 0.f, 0.f, 0.f};
  float s2[NS] = {0.f, 0.f, 0.f, 0.f};
  const float* __restrict__ xp = x + (size_t)bi * TLEN;
  float* __restrict__ op       = out + (size_t)bi * TLEN;
  for (int t = 0; t < TLEN; t += 4) {
    const float4 xv = *reinterpret_cast<const float4*>(xp + t);
    float ys[4];
    ys[0] = step_cascade(xv.x, b0, b1, b2, a1, a2, s1, s2);
    ys[1] = step_cascade(xv.y, b0, b1, b2, a1, a2, s1, s2);
    ys[2] = step_cascade(xv.z, b0, b1, b2, a1, a2, s1, s2);
    ys[3] = step_cascade(xv.w, b0, b1, b2, a1, a2, s1, s2);
    *reinterpret_cast<float4*>(op + t) = make_float4(ys[0], ys[1], ys[2], ys[3]);
  }
}

// ---------------------------------------------------------------------------
template <int P, int LOG2P>
static void run_pipeline(const float* x, const float* bc, const float* ac,
                         float* out, void* d_ws, hipStream_t stream) {
  constexpr int LOG2L   = LOG2T - LOG2P;
  constexpr int THREADS = (P > 256) ? P : 256;
  float* vbuf = (float*)d_ws;                          // BATCH*P*8 floats
  float* Mmat = vbuf + (size_t)BATCH * P * NSTATE;     // LOG2P*64 floats

  k_build_M<LOG2L, LOG2P><<<1, 64, 0, stream>>>(bc, ac, Mmat);
  k_chunk_state<P><<<(BATCH * P) / 256, 256, 0, stream>>>(x, bc, ac, vbuf);
  k_scan_par<P, LOG2P>
      <<<(BATCH * P) / THREADS, THREADS, 0, stream>>>(Mmat, vbuf);
  k_chunk_out<P><<<(BATCH * P) / 256, 256, 0, stream>>>(x, bc, ac, vbuf, out);
}

extern "C" void kernel_launch(void* const* d_in, const int* in_sizes, int n_in,
                              void* d_out, int out_size, void* d_ws, size_t ws_size,
                              hipStream_t stream) {
  const float* x  = (const float*)d_in[0];  // (B, T, 1)
  const float* bc = (const float*)d_in[1];  // (NS, 3)
  const float* ac = (const float*)d_in[2];  // (NS, 2)
  float* out = (float*)d_out;               // (B, T, 1)

  const size_t need512 = ((size_t)BATCH * 512 * NSTATE + 9 * 64) * sizeof(float);
  const size_t need256 = ((size_t)BATCH * 256 * NSTATE + 8 * 64) * sizeof(float);
  const size_t need128 = ((size_t)BATCH * 128 * NSTATE + 7 * 64) * sizeof(float);

  if (ws_size >= need512) {
    run_pipeline<512, 9>(x, bc, ac, out, d_ws, stream);
  } else if (ws_size >= need256) {
    run_pipeline<256, 8>(x, bc, ac, out, d_ws, stream);
  } else if (ws_size >= need128) {
    run_pipeline<128, 7>(x, bc, ac, out, d_ws, stream);
  } else {
    k_naive<<<(BATCH + 255) / 256, 256, 0, stream>>>(x, bc, ac, out);
  }
}